// Round 6
// baseline (174.368 us; speedup 1.0000x reference)
//
#include <hip/hip_runtime.h>
#include <hip/hip_cooperative_groups.h>

namespace cg = cooperative_groups;

#define DM 2048
#define DS 16
#define SEQ 4096
#define P 4096      // batch * d_model independent scans
#define NC 32       // chunks
#define LST 128     // SEQ / NC, per-thread register-resident x
#define UNR 8

// Rescaled state: g' = Abar*g + x ; y = sum_n CB[n]*g[n] + D*x,  CB = C*delta*B.
// ws layout (floats), S = DS*DM:
//   [0,   S)  Abar [DS][DM]
//   [S,  2S)  CB   [DS][DM]
//   [2S, 3S)  PowL [DS][DM]  (Abar^LST)
//   [3S, ..)  Hloc [NC][DS][P]

__global__ __launch_bounds__(256) void k_params(const float* __restrict__ A_log,
                                                const float* __restrict__ B,
                                                const float* __restrict__ C,
                                                const float* __restrict__ delta,
                                                float* __restrict__ ws) {
  int j = blockIdx.x * 256 + threadIdx.x;
  if (j >= DM * DS) return;
  int n = j / DM, d = j - n * DM;
  float dl = delta[d];
  float a = -expf(A_log[d * DS + n]);
  ws[j] = expf(dl * a);                                 // Abar
  ws[DS * DM + j] = C[d * DS + n] * dl * B[d * DS + n]; // CB
  ws[2 * DS * DM + j] = expf(dl * a * (float)LST);      // Abar^LST
}

// ---- fused cooperative kernel: x read once, held in registers ----
__global__ __launch_bounds__(256, 2) void k_fused(const float* __restrict__ x,
                                                  const float* __restrict__ ws,
                                                  float* __restrict__ Hloc,
                                                  const float* __restrict__ Dp,
                                                  float* __restrict__ out) {
  int bid = blockIdx.x;
  int k = bid >> 4;                       // 16 blocks per chunk
  int p = ((bid & 15) << 8) + threadIdx.x;
  int d = p & (DM - 1);
  int b = p >> 11;

  const float* Abar = ws;
  float ab[DS];
#pragma unroll
  for (int n = 0; n < DS; n++) ab[n] = Abar[n * DM + d];

  // Phase A: load x chunk into registers (interleaved with scan to bound
  // peak register pressure); local scan from g=0.
  const float* xp = x + ((size_t)b * SEQ + (size_t)k * LST) * DM + d;
  float xr[LST];
  float g[DS];
#pragma unroll
  for (int n = 0; n < DS; n++) g[n] = 0.f;
#pragma unroll
  for (int t0 = 0; t0 < LST; t0 += 16) {
#pragma unroll
    for (int j = 0; j < 16; j++) xr[t0 + j] = xp[(size_t)(t0 + j) * DM];
#pragma unroll
    for (int j = 0; j < 16; j++) {
#pragma unroll
      for (int n = 0; n < DS; n++) g[n] = fmaf(ab[n], g[n], xr[t0 + j]);
    }
  }
  float* Hp = Hloc + (size_t)(k * DS) * P + p;
#pragma unroll
  for (int n = 0; n < DS; n++) Hp[n * P] = g[n];

  cg::this_grid().sync();

  // Phase B: exclusive prefix scan over chunks, threads (n,p).
  int tid = bid * 256 + threadIdx.x;
  if (tid < DS * P) {
    int pp = tid & (P - 1);
    int n = tid >> 12;
    int dd = pp & (DM - 1);
    const float* PowL = ws + 2 * DS * DM;
    float pw = PowL[n * DM + dd];
    float carry = 0.f;
    float* Sp = Hloc + (size_t)n * P + pp;
    const size_t stride = (size_t)DS * P;
#pragma unroll
    for (int k0 = 0; k0 < NC; k0 += 16) {
      float v[16];
#pragma unroll
      for (int j = 0; j < 16; j++) v[j] = Sp[(size_t)(k0 + j) * stride];
#pragma unroll
      for (int j = 0; j < 16; j++) {
        Sp[(size_t)(k0 + j) * stride] = carry;
        carry = fmaf(pw, carry, v[j]);
      }
    }
  }

  cg::this_grid().sync();

  // Phase C: rescan from true start state, emit y.
  const float* CB = ws + DS * DM;
  float cb[DS];
#pragma unroll
  for (int n = 0; n < DS; n++) cb[n] = CB[n * DM + d];
#pragma unroll
  for (int n = 0; n < DS; n++) g[n] = Hp[n * P];
  float Dd = Dp[d];
  float* yp = out + ((size_t)b * SEQ + (size_t)k * LST) * DM + d;
#pragma unroll
  for (int t = 0; t < LST; t++) {
#pragma unroll
    for (int n = 0; n < DS; n++) g[n] = fmaf(ab[n], g[n], xr[t]);
    float acc = Dd * xr[t];
#pragma unroll
    for (int n = 0; n < DS; n++) acc = fmaf(cb[n], g[n], acc);
    yp[(size_t)t * DM] = acc;
  }
}

// ---- fallback path (R4 structure, proven 53 µs) ----
__global__ __launch_bounds__(256) void k_local(const float* __restrict__ x,
                                               const float* __restrict__ ws,
                                               float* __restrict__ Hloc, int Lsteps) {
  int tid = blockIdx.x * 256 + threadIdx.x;
  int p = tid & (P - 1);
  int k = tid >> 12;
  int b = p >> 11;
  int d = p & (DM - 1);
  const float* Abar = ws;
  float ab[DS], g[DS];
#pragma unroll
  for (int n = 0; n < DS; n++) {
    ab[n] = Abar[n * DM + d];
    g[n] = 0.f;
  }
  const float* xp = x + ((size_t)b * SEQ + (size_t)k * Lsteps) * DM + d;
  for (int t = 0; t < Lsteps; t += UNR) {
    float xv[UNR];
#pragma unroll
    for (int j = 0; j < UNR; j++) xv[j] = xp[(size_t)j * DM];
#pragma unroll
    for (int j = 0; j < UNR; j++) {
#pragma unroll
      for (int n = 0; n < DS; n++) g[n] = fmaf(ab[n], g[n], xv[j]);
    }
    xp += (size_t)UNR * DM;
  }
  float* Hp = Hloc + (size_t)(k * DS) * P + p;
#pragma unroll
  for (int n = 0; n < DS; n++) Hp[n * P] = g[n];
}

__global__ __launch_bounds__(256) void k_scan(float* __restrict__ Hloc,
                                              const float* __restrict__ ws, int nc) {
  int tid = blockIdx.x * 256 + threadIdx.x;
  int p = tid & (P - 1);
  int n = tid >> 12;
  int d = p & (DM - 1);
  const float* PowL = ws + 2 * DS * DM;
  float pw = PowL[n * DM + d];
  float carry = 0.f;
  float* Hp = Hloc + (size_t)n * P + p;
  const size_t stride = (size_t)DS * P;
  for (int k0 = 0; k0 < nc; k0 += 16) {
    float v[16];
#pragma unroll
    for (int j = 0; j < 16; j++) v[j] = Hp[(size_t)(k0 + j) * stride];
#pragma unroll
    for (int j = 0; j < 16; j++) {
      Hp[(size_t)(k0 + j) * stride] = carry;
      carry = fmaf(pw, carry, v[j]);
    }
  }
}

__global__ __launch_bounds__(256) void k_final(const float* __restrict__ x,
                                               const float* __restrict__ ws,
                                               const float* __restrict__ Hloc,
                                               const float* __restrict__ Dp,
                                               float* __restrict__ out, int Lsteps) {
  int tid = blockIdx.x * 256 + threadIdx.x;
  int p = tid & (P - 1);
  int k = tid >> 12;
  int b = p >> 11;
  int d = p & (DM - 1);
  const float* Abar = ws;
  const float* CB = ws + DS * DM;
  float ab[DS], cb[DS], g[DS];
#pragma unroll
  for (int n = 0; n < DS; n++) {
    ab[n] = Abar[n * DM + d];
    cb[n] = CB[n * DM + d];
  }
  const float* Hp = Hloc + (size_t)(k * DS) * P + p;
#pragma unroll
  for (int n = 0; n < DS; n++) g[n] = Hp[n * P];
  float Dd = Dp[d];
  size_t off = ((size_t)b * SEQ + (size_t)k * Lsteps) * DM + d;
  const float* xp = x + off;
  float* yp = out + off;
  for (int t = 0; t < Lsteps; t += UNR) {
    float xv[UNR];
#pragma unroll
    for (int j = 0; j < UNR; j++) xv[j] = xp[(size_t)j * DM];
#pragma unroll
    for (int j = 0; j < UNR; j++) {
#pragma unroll
      for (int n = 0; n < DS; n++) g[n] = fmaf(ab[n], g[n], xv[j]);
      float acc = Dd * xv[j];
#pragma unroll
      for (int n = 0; n < DS; n++) acc = fmaf(cb[n], g[n], acc);
      yp[(size_t)j * DM] = acc;
    }
    xp += (size_t)UNR * DM;
    yp += (size_t)UNR * DM;
  }
}

extern "C" void kernel_launch(void* const* d_in, const int* in_sizes, int n_in,
                              void* d_out, int out_size, void* d_ws, size_t ws_size,
                              hipStream_t stream) {
  const float* x = (const float*)d_in[0];
  const float* A_log = (const float*)d_in[1];
  const float* B = (const float*)d_in[2];
  const float* C = (const float*)d_in[3];
  const float* Dp = (const float*)d_in[4];
  const float* delta = (const float*)d_in[5];
  float* out = (float*)d_out;
  float* ws = (float*)d_ws;
  float* Hloc = ws + 3 * (size_t)DS * DM;

  k_params<<<(DM * DS + 255) / 256, 256, 0, stream>>>(A_log, B, C, delta, ws);

  void* args[] = {(void*)&x, (void*)&ws, (void*)&Hloc, (void*)&Dp, (void*)&out};
  hipError_t err = hipLaunchCooperativeKernel((void*)k_fused, dim3(NC * 16), dim3(256),
                                              args, 0, stream);
  if (err != hipSuccess) {
    (void)hipGetLastError();  // clear sticky error; fall back to 3-kernel path
    k_local<<<(NC * P) / 256, 256, 0, stream>>>(x, ws, Hloc, LST);
    k_scan<<<(DS * P) / 256, 256, 0, stream>>>(Hloc, ws, NC);
    k_final<<<(NC * P) / 256, 256, 0, stream>>>(x, ws, Hloc, Dp, out, LST);
  }
}

// Round 7
// 48.017 us; speedup vs baseline: 3.6314x; 3.6314x over previous
//
#include <hip/hip_runtime.h>

#define DM 2048
#define DS 16
#define SEQ 4096
#define P 4096      // batch * d_model independent scans
#define NC 32       // chunks
#define LST 128     // SEQ / NC
#define UNR 16

// Rescaled state: g' = Abar*g + x  (Abar = exp(-delta*exp(A_log)));
// y = sum_n CB[n]*g[n] + D*x, CB = C*delta*B.
// All params computed inline per-thread (no k_params kernel).
// ws layout (floats): Hloc [NC][DS][P]

__device__ __forceinline__ void load_ab(const float* __restrict__ A_log, int d,
                                        float dl, float* ab) {
  const float4* alp = (const float4*)(A_log + d * DS);
#pragma unroll
  for (int q = 0; q < 4; q++) {
    float4 v = alp[q];
    ab[4 * q + 0] = __expf(-dl * __expf(v.x));
    ab[4 * q + 1] = __expf(-dl * __expf(v.y));
    ab[4 * q + 2] = __expf(-dl * __expf(v.z));
    ab[4 * q + 3] = __expf(-dl * __expf(v.w));
  }
}

// Phase 1: per-chunk local scan from g=0; store g at chunk end.
__global__ __launch_bounds__(256) void k_local(const float* __restrict__ x,
                                               const float* __restrict__ A_log,
                                               const float* __restrict__ delta,
                                               float* __restrict__ Hloc) {
  int tid = blockIdx.x * 256 + threadIdx.x;
  int p = tid & (P - 1);
  int k = tid >> 12;
  int b = p >> 11;
  int d = p & (DM - 1);
  float dl = delta[d];
  float ab[DS], g[DS];
  load_ab(A_log, d, dl, ab);
#pragma unroll
  for (int n = 0; n < DS; n++) g[n] = 0.f;

  const float* xp = x + ((size_t)b * SEQ + (size_t)k * LST) * DM + d;
#pragma unroll 1
  for (int t = 0; t < LST; t += UNR) {
    float xv[UNR];
#pragma unroll
    for (int j = 0; j < UNR; j++) xv[j] = xp[(size_t)j * DM];
#pragma unroll
    for (int j = 0; j < UNR; j++) {
#pragma unroll
      for (int n = 0; n < DS; n++) g[n] = fmaf(ab[n], g[n], xv[j]);
    }
    xp += (size_t)UNR * DM;
  }
  if (k < NC - 1) {  // last chunk-end state is never consumed (exclusive scan)
    float* Hp = Hloc + (size_t)(k * DS) * P + p;
#pragma unroll
    for (int n = 0; n < DS; n++) Hp[n * P] = g[n];
  }
}

// Phase 2: exclusive prefix scan over chunks, parallel over (n,p).
__global__ __launch_bounds__(256) void k_scan(float* __restrict__ Hloc,
                                              const float* __restrict__ A_log,
                                              const float* __restrict__ delta) {
  int tid = blockIdx.x * 256 + threadIdx.x;  // DS*P threads
  int p = tid & (P - 1);
  int n = tid >> 12;
  int d = p & (DM - 1);
  float dl = delta[d];
  float pw = __expf(-dl * __expf(A_log[d * DS + n]) * (float)LST);  // Abar^LST
  float carry = 0.f;
  float* Hp = Hloc + (size_t)n * P + p;
  const size_t stride = (size_t)DS * P;
#pragma unroll
  for (int k0 = 0; k0 < NC; k0 += 16) {
    float v[16];
#pragma unroll
    for (int j = 0; j < 16; j++) v[j] = Hp[(size_t)(k0 + j) * stride];
#pragma unroll
    for (int j = 0; j < 16; j++) {
      Hp[(size_t)(k0 + j) * stride] = carry;
      carry = fmaf(pw, carry, v[j]);
    }
  }
}

// Phase 3: rescan each chunk from its true start state; emit y.
__global__ __launch_bounds__(256) void k_final(const float* __restrict__ x,
                                               const float* __restrict__ A_log,
                                               const float* __restrict__ B,
                                               const float* __restrict__ C,
                                               const float* __restrict__ Dp,
                                               const float* __restrict__ delta,
                                               const float* __restrict__ Hloc,
                                               float* __restrict__ out) {
  int tid = blockIdx.x * 256 + threadIdx.x;
  int p = tid & (P - 1);
  int k = tid >> 12;
  int b = p >> 11;
  int d = p & (DM - 1);
  float dl = delta[d];
  float ab[DS], cb[DS], g[DS];
  load_ab(A_log, d, dl, ab);
  {
    const float4* bp = (const float4*)(B + d * DS);
    const float4* cp = (const float4*)(C + d * DS);
#pragma unroll
    for (int q = 0; q < 4; q++) {
      float4 bv = bp[q];
      float4 cv = cp[q];
      cb[4 * q + 0] = cv.x * dl * bv.x;
      cb[4 * q + 1] = cv.y * dl * bv.y;
      cb[4 * q + 2] = cv.z * dl * bv.z;
      cb[4 * q + 3] = cv.w * dl * bv.w;
    }
  }
  const float* Hp = Hloc + (size_t)(k * DS) * P + p;
#pragma unroll
  for (int n = 0; n < DS; n++) g[n] = Hp[n * P];
  float Dd = Dp[d];
  size_t off = ((size_t)b * SEQ + (size_t)k * LST) * DM + d;
  const float* xp = x + off;
  float* yp = out + off;
#pragma unroll 1
  for (int t = 0; t < LST; t += UNR) {
    float xv[UNR];
#pragma unroll
    for (int j = 0; j < UNR; j++) xv[j] = xp[(size_t)j * DM];
#pragma unroll
    for (int j = 0; j < UNR; j++) {
#pragma unroll
      for (int n = 0; n < DS; n++) g[n] = fmaf(ab[n], g[n], xv[j]);
      float acc = Dd * xv[j];
#pragma unroll
      for (int n = 0; n < DS; n++) acc = fmaf(cb[n], g[n], acc);
      yp[(size_t)j * DM] = acc;
    }
    xp += (size_t)UNR * DM;
    yp += (size_t)UNR * DM;
  }
}

extern "C" void kernel_launch(void* const* d_in, const int* in_sizes, int n_in,
                              void* d_out, int out_size, void* d_ws, size_t ws_size,
                              hipStream_t stream) {
  const float* x = (const float*)d_in[0];
  const float* A_log = (const float*)d_in[1];
  const float* B = (const float*)d_in[2];
  const float* C = (const float*)d_in[3];
  const float* Dp = (const float*)d_in[4];
  const float* delta = (const float*)d_in[5];
  float* out = (float*)d_out;
  float* Hloc = (float*)d_ws;

  // Phase A: exclusive-scan chunk states; Phase B: prefix; Phase C: rescan+emit.
  k_local<<<(NC * P) / 256, 256, 0, stream>>>(x, A_log, delta, Hloc);
  k_scan<<<(DS * P) / 256, 256, 0, stream>>>(Hloc, A_log, delta);
  k_final<<<(NC * P) / 256, 256, 0, stream>>>(x, A_log, B, C, Dp, delta, Hloc, out);
}